// Round 13
// baseline (648.636 us; speedup 1.0000x reference)
//
#include <hip/hip_runtime.h>
#include <hip/hip_bf16.h>
#include <hip/hip_fp16.h>

// I/O f32. Internal: bf16 MFMA GEMMs, f16 value/off/aw + packed-f16 sampling,
// bf16 residual path (threshold 9.9e-2 budgets low-precision internals).
// Levels (100,100),(50,50),(25,25),(13,13),(7,7); offsets 0,10000,12500,13125,13294
#define LTOT 13343
#define NLQ  26686
// fixed workspace byte offsets (used inside EPI7 epilogue)
#define WS_VALB 27326464
#define WS_R    122969088
#define WS_AW   (WS_R + 17079040)
#define WS_REF  (WS_R + 25618560)

typedef __attribute__((ext_vector_type(8))) short bf16x8;
typedef __attribute__((ext_vector_type(4))) float f32x4;
typedef _Float16 f16x2 __attribute__((ext_vector_type(2)));

__device__ __forceinline__ short f2bs(float x) {
  __hip_bfloat16 h = __float2bfloat16(x);
  return __builtin_bit_cast(short, h);
}
__device__ __forceinline__ float b2f(__hip_bfloat16 x) { return __bfloat162float(x); }
__device__ __forceinline__ unsigned short f2bu(float x) {
  return __builtin_bit_cast(unsigned short, __float2bfloat16(x));
}

// async global->LDS 16B per lane; LDS dst must be wave-uniform base (+lane*16)
__device__ __forceinline__ void gld16(const void* g, void* l) {
  __builtin_amdgcn_global_load_lds(
      (const __attribute__((address_space(1))) void*)g,
      (__attribute__((address_space(3))) void*)l, 16, 0, 0);
}

// ---------------------------------------------------------------------------
// MFMA GEMM: out = epi(A(bf16) @ W^T + bias)
// MT=128: 128x128 tile, 4 waves 64x64; MT=64: 64x128 tile, 4 waves 64x32.
// FAST path (AMODE0/WMODE0): BK=64 double-panel staging, one barrier pair per
// 64-K. LDS: MT128 32KB, MT64 24KB. Legacy BK=32 path for conv4.
// EPI: 0 bias->f32 rowmap | 1 bias+sigmoid->f32 | 2 bias+relu->bf16 rowmap
//      3 atomicAdd f32 | 4 bias->f32 NCHW | 6 bias->bf16 rowmap
//      7 fused projection (val f16|off f16|aw f16|ref sigmoid f32)
//      8 bias + residual(bf16) -> bf16 rowmap
// ---------------------------------------------------------------------------
template<int MT, int AMODE, int EPI, int WMODE>
__global__ __launch_bounds__(256) void mgemm_k(
    const __hip_bfloat16* __restrict__ A, const void* __restrict__ Wv,
    const float* __restrict__ bias, void* __restrict__ outv,
    const __hip_bfloat16* __restrict__ resid,
    int M, int Nc, int K, int k_len,
    int A_HW, int A_L, int A_off,
    int O_HW, int O_L, int O_off)
{
  constexpr int JF = (MT == 128) ? 4 : 2;
  constexpr bool FAST = (AMODE == 0 && WMODE == 0);
  constexpr int AK = FAST ? 64 : 32;
  constexpr int PA = MT * 32;
  constexpr int PB = 4096;
  __shared__ __hip_bfloat16 ldsA[MT * AK];
  __shared__ __hip_bfloat16 ldsB[128 * AK];
  const int t = threadIdx.x;
  const int bm = blockIdx.x * MT, bn = blockIdx.y * 128;
  const int k0 = blockIdx.z * k_len;

  const int sl = t & 63;
  const int mloc = sl & 15;
  const int kbase = (sl >> 4) * 8;
  const int s0 = t >> 6;

  const int r0 = bm + s0 * 16 + mloc, r1 = r0 + 64;
  const int nc0 = bn + s0 * 16 + mloc, nc1 = nc0 + 64;

  const __hip_bfloat16 *ap0 = A, *ap1 = A;
  bool av0 = false, av1 = false;
  int g0n=0, g0h=0, g0w=0, g1n=0, g1h=0, g1w=0;
  if (AMODE == 0) {
    if (r0 < M) { int nn = r0 / A_HW, p = r0 - nn * A_HW;
      ap0 = A + (size_t)(nn * A_L + A_off + p) * K + kbase; av0 = true; }
    if (MT == 128 && r1 < M) { int nn = r1 / A_HW, p = r1 - nn * A_HW;
      ap1 = A + (size_t)(nn * A_L + A_off + p) * K + kbase; av1 = true; }
  } else {
    if (r0 < M) { g0n = r0 / 49; int p = r0 - g0n * 49; g0h = p / 7; g0w = p - g0h * 7; av0 = true; }
    if (r1 < M) { g1n = r1 / 49; int p = r1 - g1n * 49; g1h = p / 7; g1w = p - g1h * 7; av1 = true; }
  }
  const bool wv0 = nc0 < Nc, wv1 = nc1 < Nc;
  const __hip_bfloat16 *wb0 = (const __hip_bfloat16*)Wv, *wb1 = wb0;
  const float *wf0 = (const float*)Wv, *wf1 = wf0;
  if (WMODE == 0) {
    if (wv0) wb0 = (const __hip_bfloat16*)Wv + (size_t)nc0 * K + kbase;
    if (wv1) wb1 = (const __hip_bfloat16*)Wv + (size_t)nc1 * K + kbase;
  } else {
    if (wv0) wf0 = (const float*)Wv + (size_t)nc0 * 9216;
    if (wv1) wf1 = (const float*)Wv + (size_t)nc1 * 9216;
  }

  __hip_bfloat16* lbA0 = ldsA + s0 * 512;
  __hip_bfloat16* lbA1 = lbA0 + 2048;
  __hip_bfloat16* lbB0 = ldsB + s0 * 512;
  __hip_bfloat16* lbB1 = lbB0 + 2048;
  __hip_bfloat16* lwA0 = ldsA + s0 * 512 + sl * 8;
  __hip_bfloat16* lwA1 = lwA0 + 2048;
  __hip_bfloat16* lwB0 = ldsB + s0 * 512 + sl * 8;
  __hip_bfloat16* lwB1 = lwB0 + 2048;

  const int lane = t & 63, wv_ = t >> 6;
  const __hip_bfloat16 *rA, *rB;
  int wmR, colbase;
  if (MT == 128) {
    int wm = wv_ >> 1, wn = wv_ & 1;
    rA = ldsA + wm * 2048 + lane * 8;
    rB = ldsB + wn * 2048 + lane * 8;
    wmR = wm * 64;
    colbase = bn + wn * 64;
  } else {
    rA = ldsA + lane * 8;
    rB = ldsB + wv_ * 1024 + lane * 8;
    wmR = 0;
    colbase = bn + wv_ * 32;
  }

  f32x4 acc[4][JF] = {};

  if (FAST) {
    for (int kt = k0; kt < k0 + k_len; kt += 64) {
      if (av0) { gld16(ap0 + kt, lbA0); gld16(ap0 + kt + 32, lbA0 + PA); }
      if (MT == 128) {
        if (av1) { gld16(ap1 + kt, lbA1); gld16(ap1 + kt + 32, lbA1 + PA); }
      }
      if (wv0) { gld16(wb0 + kt, lbB0); gld16(wb0 + kt + 32, lbB0 + PB); }
      if (wv1) { gld16(wb1 + kt, lbB1); gld16(wb1 + kt + 32, lbB1 + PB); }
      __syncthreads();
#pragma unroll
      for (int h = 0; h < 2; h++) {
        bf16x8 af[4], bfr[JF];
#pragma unroll
        for (int i = 0; i < 4; i++) af[i] = *(const bf16x8*)(rA + h * PA + i * 512);
#pragma unroll
        for (int j = 0; j < JF; j++) bfr[j] = *(const bf16x8*)(rB + h * PB + j * 512);
#pragma unroll
        for (int i = 0; i < 4; i++)
#pragma unroll
          for (int j = 0; j < JF; j++)
            acc[i][j] = __builtin_amdgcn_mfma_f32_16x16x32_bf16(af[i], bfr[j], acc[i][j], 0, 0, 0);
      }
      __syncthreads();
    }
  } else {
    for (int kt = k0; kt < k0 + k_len; kt += 32) {
      {
        bf16x8 va0 = {}, va1 = {};
        int kp = kt + kbase;
        int rs = kp >> 10, c = kp & 1023;
        int rr = rs / 3, ss = rs - rr * 3;
        if (av0) { int ih = g0h*2-1+rr, iw = g0w*2-1+ss;
          if ((unsigned)ih < 13u && (unsigned)iw < 13u)
            va0 = *(const bf16x8*)(A + ((size_t)(g0n*169 + ih*13 + iw))*1024 + c); }
        if (av1) { int ih = g1h*2-1+rr, iw = g1w*2-1+ss;
          if ((unsigned)ih < 13u && (unsigned)iw < 13u)
            va1 = *(const bf16x8*)(A + ((size_t)(g1n*169 + ih*13 + iw))*1024 + c); }
        *(bf16x8*)lwA0 = va0;  *(bf16x8*)lwA1 = va1;
      }
      {
        bf16x8 vb0 = {}, vb1 = {};
        int kp = kt + kbase;
        int rs = kp >> 10, c = kp & 1023;
        if (wv0) { const float* p = wf0 + (size_t)c * 9 + rs;
#pragma unroll
          for (int j = 0; j < 8; j++) vb0[j] = f2bs(p[j * 9]); }
        if (wv1) { const float* p = wf1 + (size_t)c * 9 + rs;
#pragma unroll
          for (int j = 0; j < 8; j++) vb1[j] = f2bs(p[j * 9]); }
        *(bf16x8*)lwB0 = vb0;  *(bf16x8*)lwB1 = vb1;
      }
      __syncthreads();
      bf16x8 af[4], bfr[JF];
#pragma unroll
      for (int i = 0; i < 4; i++) af[i] = *(const bf16x8*)(rA + i * 512);
#pragma unroll
      for (int j = 0; j < JF; j++) bfr[j] = *(const bf16x8*)(rB + j * 512);
#pragma unroll
      for (int i = 0; i < 4; i++)
#pragma unroll
        for (int j = 0; j < JF; j++)
          acc[i][j] = __builtin_amdgcn_mfma_f32_16x16x32_bf16(af[i], bfr[j], acc[i][j], 0, 0, 0);
      __syncthreads();
    }
  }

  // epilogue: C/D map col=lane&15, row=(lane>>4)*4+reg
  const int quad = lane >> 4, nl = lane & 15;
  float bv[JF]; int cj[JF]; bool cv[JF];
#pragma unroll
  for (int j = 0; j < JF; j++) {
    cj[j] = colbase + j * 16 + nl;
    cv[j] = cj[j] < Nc;
    bv[j] = (EPI != 3 && cv[j]) ? bias[cj[j]] : 0.f;
  }
#pragma unroll
  for (int i = 0; i < 4; i++) {
#pragma unroll
    for (int r = 0; r < 4; r++) {
      int m = bm + wmR + i * 16 + quad * 4 + r;
      if (m >= M) continue;
      int n = m / O_HW, p = m - n * O_HW;
      size_t orow = (size_t)(n * O_L + O_off + p);
#pragma unroll
      for (int j = 0; j < JF; j++) {
        if (!cv[j]) continue;
        float v = acc[i][j][r] + bv[j];
        if (EPI == 1) v = 1.f / (1.f + expf(-v));
        if (EPI == 2) v = fmaxf(v, 0.f);
        if (EPI == 0 || EPI == 1) ((float*)outv)[orow * Nc + cj[j]] = v;
        else if (EPI == 2 || EPI == 6) ((__hip_bfloat16*)outv)[orow * Nc + cj[j]] = __float2bfloat16(v);
        else if (EPI == 3) atomicAdd((float*)outv + orow * Nc + cj[j], acc[i][j][r]);
        else if (EPI == 8) {
          float rv = b2f(resid[orow * Nc + cj[j]]);
          ((__hip_bfloat16*)outv)[orow * Nc + cj[j]] = __float2bfloat16(v + rv);
        }
        else if (EPI == 7) {
          char* base = (char*)outv;
          int q = m, c = cj[j];
          if (c < 256)
            ((_Float16*)(base + WS_VALB))[(size_t)q * 256 + c] = (_Float16)v;
          else if (c < 576)
            ((_Float16*)(base + WS_R))[(size_t)q * 320 + (c - 256)] = (_Float16)v;
          else if (c < 736)
            ((_Float16*)(base + WS_AW))[(size_t)q * 160 + (c - 576)] = (_Float16)v;
          else {
            float sv = 1.f / (1.f + expf(-v));
            ((float*)(base + WS_REF))[(size_t)q * 10 + (c - 736)] = sv;
          }
        }
        else ((float*)outv)[((size_t)n * Nc + cj[j]) * O_HW + p] = v;
      }
    }
  }
}

// bulk f32->bf16 weight conversion + bias concat + stats zero + conv4 bias init
struct CvtEnt { const float* s; __hip_bfloat16* d; int n; };
struct CvtTab { CvtEnt e[13]; };
__global__ __launch_bounds__(256) void cvt_weights_k(CvtTab tab,
    const float* __restrict__ bv, const float* __restrict__ bo,
    const float* __restrict__ ba, const float* __restrict__ br,
    float* __restrict__ catbias, float* __restrict__ stats,
    float* __restrict__ src, const float* __restrict__ bc4)
{
  int i = blockIdx.x * 256 + threadIdx.x;
  if (blockIdx.y == 13) {
    if (i < 746) {
      float v;
      if (i < 256) v = bv[i];
      else if (i < 576) v = bo[i - 256];
      else if (i < 736) v = ba[i - 576];
      else v = br[i - 736];
      catbias[i] = v;
    }
    if (i < 512) stats[i] = 0.f;
    return;
  }
  if (blockIdx.y == 14) {
    if (i < 25088) {   // 98 rows x 256 ch: conv4 bias init
      int blk = i >> 8, c = i & 255;
      int n = blk / 49, p = blk - n * 49;
      src[((size_t)(n * LTOT + 13294 + p)) * 256 + c] = bc4[c];
    }
    return;
  }
  CvtEnt E = tab.e[blockIdx.y];
  if (i < E.n) E.d[i] = __float2bfloat16(E.s[i]);
}

// fused f32 NCHW -> bf16 channel-last for x0/x2/x3 (table-driven)
__global__ __launch_bounds__(256) void transpose_all_k(
    const float* __restrict__ x0, const float* __restrict__ x2,
    const float* __restrict__ x3, __hip_bfloat16* __restrict__ xt0,
    __hip_bfloat16* __restrict__ xt2, __hip_bfloat16* __restrict__ xt3)
{
  __shared__ float tile[32][33];
  int b = blockIdx.x;
  const float* x; __hip_bfloat16* xt; int C, HW, gx, gy, n;
  if (b < 2504)      { x = x0; xt = xt0; C = 128;  HW = 10000; gx = b % 313; int r = b / 313; gy = r & 3; n = r >> 2; }
  else if (b < 3144) { int bb = b - 2504; x = x2; xt = xt2; C = 512;  HW = 625; gx = bb % 20; int r = bb / 20; gy = r & 15; n = r >> 4; }
  else               { int bb = b - 3144; x = x3; xt = xt3; C = 1024; HW = 169; gx = bb % 6;  int r = bb / 6;  gy = r & 31; n = r >> 5; }
  int p0 = gx * 32, c0 = gy * 32;
  const float* xb = x + (size_t)n * C * HW;
  __hip_bfloat16* xtb = xt + (size_t)n * HW * C;
  int tx = threadIdx.x & 31, ty = threadIdx.x >> 5;
  for (int i = ty; i < 32; i += 8) {
    int c = c0 + i, p = p0 + tx;
    tile[i][tx] = (p < HW) ? xb[(size_t)c * HW + p] : 0.f;
  }
  __syncthreads();
  for (int i = ty; i < 32; i += 8) {
    int p = p0 + i, c = c0 + tx;
    if (p < HW) xtb[(size_t)p * C + c] = __float2bfloat16(tile[tx][i]);
  }
}

// x1 (N,256,50,50) -> srcb rows [10000,12500) bf16 only
__global__ __launch_bounds__(256) void copy_lvl1_in_k(const float* __restrict__ x,
    __hip_bfloat16* __restrict__ srcb)
{
  __shared__ float tile[32][33];
  int p0 = blockIdx.x * 32, c0 = blockIdx.y * 32, n = blockIdx.z;
  int tx = threadIdx.x & 31, ty = threadIdx.x >> 5;
  for (int i = ty; i < 32; i += 8) {
    int c = c0 + i, p = p0 + tx;
    tile[i][tx] = (p < 2500) ? x[((size_t)n * 256 + c) * 2500 + p] : 0.f;
  }
  __syncthreads();
  for (int i = ty; i < 32; i += 8) {
    int p = p0 + i, c = c0 + tx;
    if (p < 2500)
      srcb[((size_t)(n * LTOT + 10000 + p)) * 256 + c] = __float2bfloat16(tile[tx][i]);
  }
}

// h2b rows [10000,12500) bf16 -> out1 (N,256,50,50) f32
__global__ __launch_bounds__(256) void copy_lvl1_out_k(const __hip_bfloat16* __restrict__ h2,
                                                       float* __restrict__ out)
{
  __shared__ float tile[32][33];
  int p0 = blockIdx.x * 32, c0 = blockIdx.y * 32, n = blockIdx.z;
  int tx = threadIdx.x & 31, ty = threadIdx.x >> 5;
  for (int i = ty; i < 32; i += 8) {
    int p = p0 + i, c = c0 + tx;
    tile[tx][i] = (p < 2500) ? b2f(h2[((size_t)(n * LTOT + 10000 + p)) * 256 + c]) : 0.f;
  }
  __syncthreads();
  for (int i = ty; i < 32; i += 8) {
    int c = c0 + i, p = p0 + tx;
    if (p < 2500) out[((size_t)n * 256 + c) * 2500 + p] = tile[i][tx];
  }
}

// GroupNorm raw sums, coalesced full-row reads; atomics into stats[64g][2]
__global__ __launch_bounds__(256) void gn_stats_k(const float* __restrict__ src,
                                                  float* __restrict__ stats)
{
  int b = blockIdx.x, n = blockIdx.y, t = threadIdx.x;
  int li, off, rr0, rend;
  if (b < 157)      { li = 0; off = 0;     rr0 = b * 64;         rend = min(rr0 + 64, 10000); }
  else if (b < 167) { li = 1; off = 12500; rr0 = (b - 157) * 64; rend = min(rr0 + 64, 625); }
  else if (b < 170) { li = 2; off = 13125; rr0 = (b - 167) * 64; rend = min(rr0 + 64, 169); }
  else              { li = 3; off = 13294; rr0 = 0;              rend = 49; }
  const float* base = src + ((size_t)(n * LTOT + off)) * 256 + t;
  float s = 0.f, s2 = 0.f;
  for (int r = rr0; r < rend; r++) {
    float v = base[(size_t)r * 256];
    s += v; s2 += v * v;
  }
  s  += __shfl_down(s, 4, 64);  s2 += __shfl_down(s2, 4, 64);
  s  += __shfl_down(s, 2, 64);  s2 += __shfl_down(s2, 2, 64);
  s  += __shfl_down(s, 1, 64);  s2 += __shfl_down(s2, 1, 64);
  if ((t & 7) == 0) {
    int g = t >> 3;
    int si = (li * 2 + n) * 32 + g;
    atomicAdd(&stats[si * 2],     s);
    atomicAdd(&stats[si * 2 + 1], s2);
  }
}

// merged GN apply + finalize -> bf16 only; grid 21686 blocks
__global__ __launch_bounds__(256) void gn_apply_k(const float* __restrict__ src,
    __hip_bfloat16* __restrict__ srcb,
    const float* __restrict__ stats, const float* __restrict__ g,
    const float* __restrict__ b)
{
  int x = blockIdx.x;
  int n = x / 10843, cidx = x - n * 10843;
  int li, off, hw, p;
  if (cidx < 10000)      { li = 0; off = 0;     hw = 10000; p = cidx; }
  else if (cidx < 10625) { li = 1; off = 12500; hw = 625;   p = cidx - 10000; }
  else if (cidx < 10794) { li = 2; off = 13125; hw = 169;   p = cidx - 10625; }
  else                   { li = 3; off = 13294; hw = 49;    p = cidx - 10794; }
  int t = threadIdx.x;
  int si = (li * 2 + n) * 32 + (t >> 3);
  float cnt = (float)(hw * 8);
  float mean = stats[si * 2] / cnt;
  float var = stats[si * 2 + 1] / cnt - mean * mean;
  float rstd = rsqrtf(var + 1e-5f);
  size_t a = ((size_t)(n * LTOT + off + p)) * 256 + t;
  float v = (src[a] - mean) * rstd * g[t] + b[t];
  srcb[a] = __float2bfloat16(v);
}

// ---------------------------------------------------------------------------
// deformable sampling v7: block = 4 queries (64 thr/query); fused softmax;
// f16 value/off/aw; gather 4 ch/thread via one dwordx2 load + 2 packed fma.
// Corner tables padded 21/head (bank-spread). LDS ~24 KB, VGPR budgeted.
// ---------------------------------------------------------------------------
__global__ __launch_bounds__(256) void msdeform_k(const _Float16* __restrict__ value,
    const _Float16* __restrict__ offb, const _Float16* __restrict__ awb,
    const float* __restrict__ refb, __hip_bfloat16* __restrict__ out)
{
  __shared__ float s_awraw[640];
  __shared__ float s_ref[40];
  __shared__ float s_stat[64];
  __shared__ int4 s_cA[672];   // (ql*8+h)*21 + pt -> off00,w00p,off10,w10p
  __shared__ int4 s_cB[672];   //                  -> off01,w01p,off11,w11p
  const int t = threadIdx.x;
  const int q0 = blockIdx.x * 4;

  // stage raw aw + ref (tail queries clamped; results discarded on store)
  for (int i = t; i < 640; i += 256) {
    int ql = i / 160;
    int q = min(q0 + ql, NLQ - 1);
    s_awraw[i] = (float)awb[(size_t)q * 160 + (i - ql * 160)];
  }
  if (t < 40) {
    int ql = t / 10;
    int q = min(q0 + ql, NLQ - 1);
    s_ref[t] = refb[(size_t)q * 10 + (t - ql * 10)];
  }
  __syncthreads();

  // per-head softmax stats (32 heads: 4 ql x 8 h)
  if (t < 32) {
    const float* p = s_awraw + t * 20;
    float m = p[0];
#pragma unroll
    for (int j = 1; j < 20; j++) m = fmaxf(m, p[j]);
    float s = 0.f;
#pragma unroll
    for (int j = 0; j < 20; j++) s += expf(p[j] - m);
    s_stat[t * 2] = m;
    s_stat[t * 2 + 1] = 1.f / s;
  }
  __syncthreads();

  // prep: 640 (ql,h,pt) items -> 4 corners (byte-offset, packed dup f16 wgt)
  {
    const int Wl[5]   = {100, 50, 25, 13, 7};
    const int lvlo[5] = {0, 10000, 12500, 13125, 13294};
    for (int i = t; i < 640; i += 256) {
      int ql = i / 160;
      int j = i - ql * 160;            // h*20+pt
      int h = j / 20, pt = j - h * 20;
      int l = pt >> 2;
      int q = min(q0 + ql, NLQ - 1);
      int W = Wl[l], lo = lvlo[l];
      float fW = (float)W;
      f16x2 o2h = *(const f16x2*)(offb + (size_t)q * 320 + j * 2);
      float ox = (float)o2h[0], oy = (float)o2h[1];
      int hs = (ql * 8 + h) * 2;
      float wgt = expf(s_awraw[i] - s_stat[hs]) * s_stat[hs + 1];
      float rx = s_ref[ql * 10 + l * 2], ry = s_ref[ql * 10 + l * 2 + 1];
      float x = (rx + ox / fW) * fW - 0.5f;
      float y = (ry + oy / fW) * fW - 0.5f;
      float x0f = floorf(x), y0f = floorf(y);
      float wx = x - x0f, wy = y - y0f;
      int x0 = (int)x0f, y0 = (int)y0f;
      int hb = h * 64;                 // head byte offset (32 ch * 2B)
      auto mk = [&](int ix, int iy, float w) {
        bool v = (ix >= 0) & (ix < W) & (iy >= 0) & (iy < W);
        int cx = min(max(ix, 0), W - 1), cy = min(max(iy, 0), W - 1);
        int off = (lo + cy * W + cx) * 512 + hb;
        float fw = v ? w * wgt : 0.f;
        unsigned hbits = (unsigned)__builtin_bit_cast(unsigned short, (_Float16)fw);
        return make_int2(off, (int)(hbits | (hbits << 16)));
      };
      int2 c00 = mk(x0,     y0,     (1.f - wx) * (1.f - wy));
      int2 c10 = mk(x0 + 1, y0,     wx * (1.f - wy));
      int2 c01 = mk(x0,     y0 + 1, (1.f - wx) * wy);
      int2 c11 = mk(x0 + 1, y0 + 1, wx * wy);
      int si = (ql * 8 + h) * 21 + pt;
      s_cA[si] = make_int4(c00.x, c00.y, c10.x, c10.y);
      s_cB[si] = make_int4(c01.x, c01.y, c11.x, c11.y);
    }
  }
  __syncthreads();

  // gather: t -> ql (t>>6), h ((t>>3)&7), c4 (t&7) -> channels c4*4..c4*4+3
  const int ql = t >> 6, h = (t >> 3) & 7, c4 = t & 7;
  const int q = q0 + ql;
  const int qc = min(q, NLQ - 1);
  const int n = qc / LTOT;
  const char* vb = (const char*)value + (size_t)n * LTOT * 512 + c4 * 8;
  f16x2 a0A = {0, 0}, a1A = {0, 0}, a0B = {0, 0}, a1B = {0, 0};
  const int bi = (ql * 8 + h) * 21;
#pragma unroll 5
  for (int p = 0; p < 20; p++) {
    int4 A = s_cA[bi + p];
    int4 B = s_cB[bi + p];
    {
      uint2 u = *(const uint2*)(vb + A.x);
      f16x2 w2 = __builtin_bit_cast(f16x2, (unsigned)A.y);
      a0A = w2 * __builtin_bit_cast(f16x2, u.x) + a0A;
      a1A = w2 * __builtin_bit_cast(f16x2, u.y) + a1A;
    }
    {
      uint2 u = *(const uint2*)(vb + A.z);
      f16x2 w2 = __builtin_bit_cast(f16x2, (unsigned)A.w);
      a0B = w2 * __builtin_bit_cast(f16x2, u.x) + a0B;
      a1B = w2 * __builtin_bit_cast(f16x2, u.y) + a1B;
    }
    {
      uint2 u = *(const uint2*)(vb + B.x);
      f16x2 w2 = __builtin_bit_cast(f16x2, (unsigned)B.y);
      a0A = w2 * __builtin_bit_cast(f16x2, u.x) + a0A;
      a1A = w2 * __builtin_bit_cast(f16x2, u.y) + a1A;
    }
    {
      uint2 u = *(const uint2*)(vb + B.z);
      f16x2 w2 = __builtin_bit_cast(f16x2, (unsigned)B.w);
      a0B = w2 * __builtin_bit_cast(f16x2, u.x) + a0B;
      a1B = w2 * __builtin_bit_cast(f16x2, u.y) + a1B;
    }
  }
  if (q < NLQ) {
    float v0 = (float)a0A[0] + (float)a0B[0];
    float v1 = (float)a0A[1] + (float)a0B[1];
    float v2 = (float)a1A[0] + (float)a1B[0];
    float v3 = (float)a1A[1] + (float)a1B[1];
    uint2 o;
    o.x = (unsigned)f2bu(v0) | ((unsigned)f2bu(v1) << 16);
    o.y = (unsigned)f2bu(v2) | ((unsigned)f2bu(v3) << 16);
    *(uint2*)((char*)out + ((size_t)q * 256 + h * 32 + c4 * 4) * 2) = o;
  }
}

// o = LayerNorm(x) over 256, bf16 I/O; wave-per-row (4 rows/block), no LDS
__global__ __launch_bounds__(256) void ln_k(const __hip_bfloat16* __restrict__ x,
    __hip_bfloat16* __restrict__ o, const float* __restrict__ g,
    const float* __restrict__ b)
{
  int wv = threadIdx.x >> 6, lane = threadIdx.x & 63;
  int row = blockIdx.x * 4 + wv;
  if (row >= NLQ) return;
  int e = lane * 4;
  ushort4 u = *(const ushort4*)((const char*)x + ((size_t)row * 256 + e) * 2);
  float v0 = __int_as_float((int)u.x << 16);
  float v1 = __int_as_float((int)u.y << 16);
  float v2 = __int_as_float((int)u.z << 16);
  float v3 = __int_as_float((int)u.w << 16);
  float s = v0 + v1 + v2 + v3;
#pragma unroll
  for (int off = 32; off; off >>= 1) s += __shfl_xor(s, off, 64);
  float mean = s * (1.f / 256.f);
  float d0 = v0 - mean, d1 = v1 - mean, d2 = v2 - mean, d3 = v3 - mean;
  float s2 = d0 * d0 + d1 * d1 + d2 * d2 + d3 * d3;
#pragma unroll
  for (int off = 32; off; off >>= 1) s2 += __shfl_xor(s2, off, 64);
  float rstd = rsqrtf(s2 * (1.f / 256.f) + 1e-5f);
  float4 gv = *(const float4*)(g + e);
  float4 bvv = *(const float4*)(b + e);
  ushort4 w;
  w.x = f2bu(d0 * rstd * gv.x + bvv.x);
  w.y = f2bu(d1 * rstd * gv.y + bvv.y);
  w.z = f2bu(d2 * rstd * gv.z + bvv.z);
  w.w = f2bu(d3 * rstd * gv.w + bvv.w);
  *(ushort4*)((char*)o + ((size_t)row * 256 + e) * 2) = w;
}

extern "C" void kernel_launch(void* const* d_in, const int* in_sizes, int n_in,
                              void* d_out, int out_size, void* d_ws, size_t ws_size,
                              hipStream_t stream)
{
  const float* x0    = (const float*)d_in[0];
  const float* x1    = (const float*)d_in[1];
  const float* x2    = (const float*)d_in[2];
  const float* x3    = (const float*)d_in[3];
  const float* W_ref = (const float*)d_in[4];
  const float* b_ref = (const float*)d_in[5];
  const float* W_off = (const float*)d_in[6];
  const float* b_off = (const float*)d_in[7];
  const float* W_aw  = (const float*)d_in[8];
  const float* b_aw  = (const float*)d_in[9];
  const float* W_val = (const float*)d_in[10];
  const float* b_val = (const float*)d_in[11];
  const float* W_outp= (const float*)d_in[12];
  const float* b_outp= (const float*)d_in[13];
  const float* gn_g  = (const float*)d_in[14];
  const float* gn_b  = (const float*)d_in[15];
  const float* Wc1   = (const float*)d_in[16];
  const float* bc1   = (const float*)d_in[17];
  const float* Wc2   = (const float*)d_in[18];
  const float* bc2   = (const float*)d_in[19];
  const float* Wc3   = (const float*)d_in[20];
  const float* bc3   = (const float*)d_in[21];
  const float* Wc4   = (const float*)d_in[22];
  const float* bc4   = (const float*)d_in[23];
  const float* Wc11  = (const float*)d_in[24];
  const float* bc11  = (const float*)d_in[25];
  const float* Wc22  = (const float*)d_in[26];
  const float* bc22  = (const float*)d_in[27];
  const float* Wc33  = (const float*)d_in[28];
  const float* bc33  = (const float*)d_in[29];
  const float* ln1_g = (const float*)d_in[30];
  const float* ln1_b = (const float*)d_in[31];
  const float* W1    = (const float*)d_in[32];
  const float* b1f   = (const float*)d_in[33];
  const float* W2    = (const float*)d_in[34];
  const float* b2f_  = (const float*)d_in[35];
  const float* ln2_g = (const float*)d_in[36];
  const float* ln2_b = (const float*)d_in[37];

  // ---- workspace (byte offsets) ----
  char* wsb = (char*)d_ws;
  float* src             = (float*)(wsb + 0);
  _Float16* valb         = (_Float16*)(wsb + WS_VALB);
  __hip_bfloat16* h1pre  = (__hip_bfloat16*)(wsb + 54652928);
  __hip_bfloat16* h2b    = h1pre;
  __hip_bfloat16* srcb   = (__hip_bfloat16*)(wsb + 81979392);
  __hip_bfloat16* h1b    = (__hip_bfloat16*)(wsb + 95642624);
  __hip_bfloat16* sampb  = (__hip_bfloat16*)(wsb + 109305856);
  __hip_bfloat16* h2pre  = sampb;
  __hip_bfloat16* midb   = (__hip_bfloat16*)(wsb + WS_R);
  _Float16* offbh        = (_Float16*)(wsb + WS_R);
  _Float16* awbh         = (_Float16*)(wsb + WS_AW);
  float* refb            = (float*)(wsb + WS_REF);
  __hip_bfloat16* xt0    = (__hip_bfloat16*)(wsb + WS_R);
  __hip_bfloat16* xt2    = (__hip_bfloat16*)(wsb + WS_R + 5120000);
  __hip_bfloat16* xt3    = (__hip_bfloat16*)(wsb + WS_R + 6400000);
  __hip_bfloat16* warena = (__hip_bfloat16*)(wsb + 177622016);
  float* stats           = (float*)(wsb + 180887552);
  float* catbias         = (float*)(wsb + 180889600);
  const size_t needed = 180892672;
  if (ws_size < needed) return;

  __hip_bfloat16* wWproj = warena + 0;
  __hip_bfloat16* wW_val = warena + 0;
  __hip_bfloat16* wW_off = warena + 65536;
  __hip_bfloat16* wW_aw  = warena + 147456;
  __hip_bfloat16* wW_ref = warena + 188416;
  __hip_bfloat16* wW_out = warena + 190976;
  __hip_bfloat16* wW1    = warena + 256512;
  __hip_bfloat16* wW2    = warena + 518656;
  __hip_bfloat16* wWc1   = warena + 780800;
  __hip_bfloat16* wWc2   = warena + 813568;
  __hip_bfloat16* wWc3   = warena + 944640;
  __hip_bfloat16* wWc11  = warena + 1206784;
  __hip_bfloat16* wWc22  = warena + 1239552;
  __hip_bfloat16* wWc33  = warena + 1370624;

  dim3 B(256);

  CvtTab tab = {{
    {W_val, wW_val, 65536}, {W_off, wW_off, 81920}, {W_aw, wW_aw, 40960},
    {W_ref, wW_ref, 2560},  {W_outp, wW_out, 65536},{W1, wW1, 262144},
    {W2, wW2, 262144},      {Wc1, wWc1, 32768},     {Wc2, wWc2, 131072},
    {Wc3, wWc3, 262144},    {Wc11, wWc11, 32768},   {Wc22, wWc22, 131072},
    {Wc33, wWc33, 262144}
  }};
  cvt_weights_k<<<dim3(1024,15),B,0,stream>>>(tab, b_val, b_off, b_aw, b_ref,
                                              catbias, stats, src, bc4);

  // ---- phase 1: fused transposes, convs, GN into src/srcb ----
  transpose_all_k<<<3528,B,0,stream>>>(x0, x2, x3, xt0, xt2, xt3);
  mgemm_k<64,0,0,0><<<dim3(313,2),B,0,stream>>>(xt0, wWc1, bc1, src, nullptr, 20000,256,128,128, 20000,0,0, 10000,LTOT,0);
  mgemm_k<64,0,0,0><<<dim3(20,2), B,0,stream>>>(xt2, wWc2, bc2, src, nullptr, 1250,256,512,512, 1250,0,0, 625,LTOT,12500);
  mgemm_k<64,0,0,0><<<dim3(6,2),  B,0,stream>>>(xt3, wWc3, bc3, src, nullptr, 338,256,1024,1024, 338,0,0, 169,LTOT,13125);
  mgemm_k<128,1,3,1><<<dim3(1,2,32),B,0,stream>>>(xt3, Wc4, bc4, src, nullptr, 98,256,9216,288, 0,0,0, 49,LTOT,13294);
  copy_lvl1_in_k<<<dim3(79,8,2),B,0,stream>>>(x1, srcb);
  gn_stats_k<<<dim3(171,2),B,0,stream>>>(src, stats);
  gn_apply_k<<<21686,B,0,stream>>>(src, srcb, stats, gn_g, gn_b);

  // ---- fused projections + sampling ----
  mgemm_k<128,0,7,0><<<dim3(209,6),B,0,stream>>>(srcb, wWproj, catbias, d_ws, nullptr, NLQ,746,256,256, NLQ,0,0, NLQ,0,0);
  msdeform_k<<<6672,B,0,stream>>>(valb, offbh, awbh, refb, sampb);

  // ---- out-proj (+resid srcb) + LN1 ----
  mgemm_k<64,0,8,0><<<dim3(417,2),B,0,stream>>>(sampb, wW_out, b_outp, h1pre, srcb, NLQ,256,256,256, NLQ,0,0, NLQ,0,0);
  ln_k<<<6672,B,0,stream>>>(h1pre, h1b, ln1_g, ln1_b);

  // ---- FFN (+resid h1b on FFN2) + LN2 ----
  mgemm_k<128,0,2,0><<<dim3(209,8),B,0,stream>>>(h1b,  wW1, b1f,  midb,  nullptr, NLQ,1024,256,256, NLQ,0,0, NLQ,0,0);
  mgemm_k<64,0,8,0><<<dim3(417,2), B,0,stream>>>(midb, wW2, b2f_, h2pre, h1b, NLQ,256,1024,1024, NLQ,0,0, NLQ,0,0);
  ln_k<<<6672,B,0,stream>>>(h2pre, h2b, ln2_g, ln2_b);

  // ---- output convs / copies (MT64) ----
  float* out = (float*)d_out;
  mgemm_k<64,0,4,0><<<dim3(313,1),B,0,stream>>>(h2b, wWc11, bc11, out,           nullptr, 20000,128,256,256, 10000,LTOT,0,   10000,0,0);
  copy_lvl1_out_k<<<dim3(79,8,2),B,0,stream>>>(h2b, out + 2560000);
  mgemm_k<64,0,4,0><<<dim3(20,4), B,0,stream>>>(h2b, wWc22, bc22, out + 3840000, nullptr, 1250,512,256,256,  625,LTOT,12500, 625,0,0);
  mgemm_k<64,0,4,0><<<dim3(6,8),  B,0,stream>>>(h2b, wWc33, bc33, out + 4480000, nullptr, 338,1024,256,256,  169,LTOT,13125, 169,0,0);
}

// Round 14
// 597.645 us; speedup vs baseline: 1.0853x; 1.0853x over previous
//
#include <hip/hip_runtime.h>
#include <hip/hip_bf16.h>
#include <hip/hip_fp16.h>

// I/O f32. Internal: bf16 MFMA GEMMs, f16 value/off/aw + packed-f16 sampling,
// bf16 residual path (threshold 9.9e-2 budgets low-precision internals).
// Levels (100,100),(50,50),(25,25),(13,13),(7,7); offsets 0,10000,12500,13125,13294
#define LTOT 13343
#define NLQ  26686
// fixed workspace byte offsets (used inside EPI7 epilogue)
#define WS_VALB 27326464
#define WS_R    122969088
#define WS_AW   (WS_R + 17079040)
#define WS_REF  (WS_R + 25618560)

typedef __attribute__((ext_vector_type(8))) short bf16x8;
typedef __attribute__((ext_vector_type(4))) float f32x4;
typedef _Float16 f16x2 __attribute__((ext_vector_type(2)));

__device__ __forceinline__ short f2bs(float x) {
  __hip_bfloat16 h = __float2bfloat16(x);
  return __builtin_bit_cast(short, h);
}
__device__ __forceinline__ float b2f(__hip_bfloat16 x) { return __bfloat162float(x); }
__device__ __forceinline__ unsigned short f2bu(float x) {
  return __builtin_bit_cast(unsigned short, __float2bfloat16(x));
}

// async global->LDS 16B per lane; LDS dst must be wave-uniform base (+lane*16)
__device__ __forceinline__ void gld16(const void* g, void* l) {
  __builtin_amdgcn_global_load_lds(
      (const __attribute__((address_space(1))) void*)g,
      (__attribute__((address_space(3))) void*)l, 16, 0, 0);
}

// ---------------------------------------------------------------------------
// MFMA GEMM: out = epi(A(bf16) @ W^T + bias)
// MT=128: 128x128 tile, 4 waves 64x64; MT=64: 64x128 tile, 4 waves 64x32.
// FAST path (AMODE0/WMODE0): BK=64 double-panel staging, one barrier pair per
// 64-K. LDS: MT128 32KB, MT64 24KB. Legacy BK=32 path for conv4.
// EPI: 0 bias->f32 rowmap | 1 bias+sigmoid->f32 | 2 bias+relu->bf16 rowmap
//      3 atomicAdd f32 | 4 bias->f32 NCHW | 6 bias->bf16 rowmap
//      7 fused projection (val f16|off f16|aw f16|ref sigmoid f32)
//      8 bias + residual(bf16) -> bf16 rowmap
// ---------------------------------------------------------------------------
template<int MT, int AMODE, int EPI, int WMODE>
__global__ __launch_bounds__(256) void mgemm_k(
    const __hip_bfloat16* __restrict__ A, const void* __restrict__ Wv,
    const float* __restrict__ bias, void* __restrict__ outv,
    const __hip_bfloat16* __restrict__ resid,
    int M, int Nc, int K, int k_len,
    int A_HW, int A_L, int A_off,
    int O_HW, int O_L, int O_off)
{
  constexpr int JF = (MT == 128) ? 4 : 2;
  constexpr bool FAST = (AMODE == 0 && WMODE == 0);
  constexpr int AK = FAST ? 64 : 32;
  constexpr int PA = MT * 32;
  constexpr int PB = 4096;
  __shared__ __hip_bfloat16 ldsA[MT * AK];
  __shared__ __hip_bfloat16 ldsB[128 * AK];
  const int t = threadIdx.x;
  const int bm = blockIdx.x * MT, bn = blockIdx.y * 128;
  const int k0 = blockIdx.z * k_len;

  const int sl = t & 63;
  const int mloc = sl & 15;
  const int kbase = (sl >> 4) * 8;
  const int s0 = t >> 6;

  const int r0 = bm + s0 * 16 + mloc, r1 = r0 + 64;
  const int nc0 = bn + s0 * 16 + mloc, nc1 = nc0 + 64;

  const __hip_bfloat16 *ap0 = A, *ap1 = A;
  bool av0 = false, av1 = false;
  int g0n=0, g0h=0, g0w=0, g1n=0, g1h=0, g1w=0;
  if (AMODE == 0) {
    if (r0 < M) { int nn = r0 / A_HW, p = r0 - nn * A_HW;
      ap0 = A + (size_t)(nn * A_L + A_off + p) * K + kbase; av0 = true; }
    if (MT == 128 && r1 < M) { int nn = r1 / A_HW, p = r1 - nn * A_HW;
      ap1 = A + (size_t)(nn * A_L + A_off + p) * K + kbase; av1 = true; }
  } else {
    if (r0 < M) { g0n = r0 / 49; int p = r0 - g0n * 49; g0h = p / 7; g0w = p - g0h * 7; av0 = true; }
    if (r1 < M) { g1n = r1 / 49; int p = r1 - g1n * 49; g1h = p / 7; g1w = p - g1h * 7; av1 = true; }
  }
  const bool wv0 = nc0 < Nc, wv1 = nc1 < Nc;
  const __hip_bfloat16 *wb0 = (const __hip_bfloat16*)Wv, *wb1 = wb0;
  const float *wf0 = (const float*)Wv, *wf1 = wf0;
  if (WMODE == 0) {
    if (wv0) wb0 = (const __hip_bfloat16*)Wv + (size_t)nc0 * K + kbase;
    if (wv1) wb1 = (const __hip_bfloat16*)Wv + (size_t)nc1 * K + kbase;
  } else {
    if (wv0) wf0 = (const float*)Wv + (size_t)nc0 * 9216;
    if (wv1) wf1 = (const float*)Wv + (size_t)nc1 * 9216;
  }

  __hip_bfloat16* lbA0 = ldsA + s0 * 512;
  __hip_bfloat16* lbA1 = lbA0 + 2048;
  __hip_bfloat16* lbB0 = ldsB + s0 * 512;
  __hip_bfloat16* lbB1 = lbB0 + 2048;
  __hip_bfloat16* lwA0 = ldsA + s0 * 512 + sl * 8;
  __hip_bfloat16* lwA1 = lwA0 + 2048;
  __hip_bfloat16* lwB0 = ldsB + s0 * 512 + sl * 8;
  __hip_bfloat16* lwB1 = lwB0 + 2048;

  const int lane = t & 63, wv_ = t >> 6;
  const __hip_bfloat16 *rA, *rB;
  int wmR, colbase;
  if (MT == 128) {
    int wm = wv_ >> 1, wn = wv_ & 1;
    rA = ldsA + wm * 2048 + lane * 8;
    rB = ldsB + wn * 2048 + lane * 8;
    wmR = wm * 64;
    colbase = bn + wn * 64;
  } else {
    rA = ldsA + lane * 8;
    rB = ldsB + wv_ * 1024 + lane * 8;
    wmR = 0;
    colbase = bn + wv_ * 32;
  }

  f32x4 acc[4][JF] = {};

  if (FAST) {
    for (int kt = k0; kt < k0 + k_len; kt += 64) {
      if (av0) { gld16(ap0 + kt, lbA0); gld16(ap0 + kt + 32, lbA0 + PA); }
      if (MT == 128) {
        if (av1) { gld16(ap1 + kt, lbA1); gld16(ap1 + kt + 32, lbA1 + PA); }
      }
      if (wv0) { gld16(wb0 + kt, lbB0); gld16(wb0 + kt + 32, lbB0 + PB); }
      if (wv1) { gld16(wb1 + kt, lbB1); gld16(wb1 + kt + 32, lbB1 + PB); }
      __syncthreads();
#pragma unroll
      for (int h = 0; h < 2; h++) {
        bf16x8 af[4], bfr[JF];
#pragma unroll
        for (int i = 0; i < 4; i++) af[i] = *(const bf16x8*)(rA + h * PA + i * 512);
#pragma unroll
        for (int j = 0; j < JF; j++) bfr[j] = *(const bf16x8*)(rB + h * PB + j * 512);
#pragma unroll
        for (int i = 0; i < 4; i++)
#pragma unroll
          for (int j = 0; j < JF; j++)
            acc[i][j] = __builtin_amdgcn_mfma_f32_16x16x32_bf16(af[i], bfr[j], acc[i][j], 0, 0, 0);
      }
      __syncthreads();
    }
  } else {
    for (int kt = k0; kt < k0 + k_len; kt += 32) {
      {
        bf16x8 va0 = {}, va1 = {};
        int kp = kt + kbase;
        int rs = kp >> 10, c = kp & 1023;
        int rr = rs / 3, ss = rs - rr * 3;
        if (av0) { int ih = g0h*2-1+rr, iw = g0w*2-1+ss;
          if ((unsigned)ih < 13u && (unsigned)iw < 13u)
            va0 = *(const bf16x8*)(A + ((size_t)(g0n*169 + ih*13 + iw))*1024 + c); }
        if (av1) { int ih = g1h*2-1+rr, iw = g1w*2-1+ss;
          if ((unsigned)ih < 13u && (unsigned)iw < 13u)
            va1 = *(const bf16x8*)(A + ((size_t)(g1n*169 + ih*13 + iw))*1024 + c); }
        *(bf16x8*)lwA0 = va0;  *(bf16x8*)lwA1 = va1;
      }
      {
        bf16x8 vb0 = {}, vb1 = {};
        int kp = kt + kbase;
        int rs = kp >> 10, c = kp & 1023;
        if (wv0) { const float* p = wf0 + (size_t)c * 9 + rs;
#pragma unroll
          for (int j = 0; j < 8; j++) vb0[j] = f2bs(p[j * 9]); }
        if (wv1) { const float* p = wf1 + (size_t)c * 9 + rs;
#pragma unroll
          for (int j = 0; j < 8; j++) vb1[j] = f2bs(p[j * 9]); }
        *(bf16x8*)lwB0 = vb0;  *(bf16x8*)lwB1 = vb1;
      }
      __syncthreads();
      bf16x8 af[4], bfr[JF];
#pragma unroll
      for (int i = 0; i < 4; i++) af[i] = *(const bf16x8*)(rA + i * 512);
#pragma unroll
      for (int j = 0; j < JF; j++) bfr[j] = *(const bf16x8*)(rB + j * 512);
#pragma unroll
      for (int i = 0; i < 4; i++)
#pragma unroll
        for (int j = 0; j < JF; j++)
          acc[i][j] = __builtin_amdgcn_mfma_f32_16x16x32_bf16(af[i], bfr[j], acc[i][j], 0, 0, 0);
      __syncthreads();
    }
  }

  // epilogue: C/D map col=lane&15, row=(lane>>4)*4+reg
  const int quad = lane >> 4, nl = lane & 15;
  float bv[JF]; int cj[JF]; bool cv[JF];
#pragma unroll
  for (int j = 0; j < JF; j++) {
    cj[j] = colbase + j * 16 + nl;
    cv[j] = cj[j] < Nc;
    bv[j] = (EPI != 3 && cv[j]) ? bias[cj[j]] : 0.f;
  }
#pragma unroll
  for (int i = 0; i < 4; i++) {
#pragma unroll
    for (int r = 0; r < 4; r++) {
      int m = bm + wmR + i * 16 + quad * 4 + r;
      if (m >= M) continue;
      int n = m / O_HW, p = m - n * O_HW;
      size_t orow = (size_t)(n * O_L + O_off + p);
#pragma unroll
      for (int j = 0; j < JF; j++) {
        if (!cv[j]) continue;
        float v = acc[i][j][r] + bv[j];
        if (EPI == 1) v = 1.f / (1.f + expf(-v));
        if (EPI == 2) v = fmaxf(v, 0.f);
        if (EPI == 0 || EPI == 1) ((float*)outv)[orow * Nc + cj[j]] = v;
        else if (EPI == 2 || EPI == 6) ((__hip_bfloat16*)outv)[orow * Nc + cj[j]] = __float2bfloat16(v);
        else if (EPI == 3) atomicAdd((float*)outv + orow * Nc + cj[j], acc[i][j][r]);
        else if (EPI == 8) {
          float rv = b2f(resid[orow * Nc + cj[j]]);
          ((__hip_bfloat16*)outv)[orow * Nc + cj[j]] = __float2bfloat16(v + rv);
        }
        else if (EPI == 7) {
          char* base = (char*)outv;
          int q = m, c = cj[j];
          if (c < 256)
            ((_Float16*)(base + WS_VALB))[(size_t)q * 256 + c] = (_Float16)v;
          else if (c < 576)
            ((_Float16*)(base + WS_R))[(size_t)q * 320 + (c - 256)] = (_Float16)v;
          else if (c < 736)
            ((_Float16*)(base + WS_AW))[(size_t)q * 160 + (c - 576)] = (_Float16)v;
          else {
            float sv = 1.f / (1.f + expf(-v));
            ((float*)(base + WS_REF))[(size_t)q * 10 + (c - 736)] = sv;
          }
        }
        else ((float*)outv)[((size_t)n * Nc + cj[j]) * O_HW + p] = v;
      }
    }
  }
}

// bulk f32->bf16 weight conversion + bias concat + stats zero + conv4 bias init
struct CvtEnt { const float* s; __hip_bfloat16* d; int n; };
struct CvtTab { CvtEnt e[13]; };
__global__ __launch_bounds__(256) void cvt_weights_k(CvtTab tab,
    const float* __restrict__ bv, const float* __restrict__ bo,
    const float* __restrict__ ba, const float* __restrict__ br,
    float* __restrict__ catbias, float* __restrict__ stats,
    float* __restrict__ src, const float* __restrict__ bc4)
{
  int i = blockIdx.x * 256 + threadIdx.x;
  if (blockIdx.y == 13) {
    if (i < 746) {
      float v;
      if (i < 256) v = bv[i];
      else if (i < 576) v = bo[i - 256];
      else if (i < 736) v = ba[i - 576];
      else v = br[i - 736];
      catbias[i] = v;
    }
    if (i < 512) stats[i] = 0.f;
    return;
  }
  if (blockIdx.y == 14) {
    if (i < 25088) {   // 98 rows x 256 ch: conv4 bias init
      int blk = i >> 8, c = i & 255;
      int n = blk / 49, p = blk - n * 49;
      src[((size_t)(n * LTOT + 13294 + p)) * 256 + c] = bc4[c];
    }
    return;
  }
  CvtEnt E = tab.e[blockIdx.y];
  if (i < E.n) E.d[i] = __float2bfloat16(E.s[i]);
}

// fused f32 NCHW -> bf16 channel-last for x0/x2/x3 (table-driven)
__global__ __launch_bounds__(256) void transpose_all_k(
    const float* __restrict__ x0, const float* __restrict__ x2,
    const float* __restrict__ x3, __hip_bfloat16* __restrict__ xt0,
    __hip_bfloat16* __restrict__ xt2, __hip_bfloat16* __restrict__ xt3)
{
  __shared__ float tile[32][33];
  int b = blockIdx.x;
  const float* x; __hip_bfloat16* xt; int C, HW, gx, gy, n;
  if (b < 2504)      { x = x0; xt = xt0; C = 128;  HW = 10000; gx = b % 313; int r = b / 313; gy = r & 3; n = r >> 2; }
  else if (b < 3144) { int bb = b - 2504; x = x2; xt = xt2; C = 512;  HW = 625; gx = bb % 20; int r = bb / 20; gy = r & 15; n = r >> 4; }
  else               { int bb = b - 3144; x = x3; xt = xt3; C = 1024; HW = 169; gx = bb % 6;  int r = bb / 6;  gy = r & 31; n = r >> 5; }
  int p0 = gx * 32, c0 = gy * 32;
  const float* xb = x + (size_t)n * C * HW;
  __hip_bfloat16* xtb = xt + (size_t)n * HW * C;
  int tx = threadIdx.x & 31, ty = threadIdx.x >> 5;
  for (int i = ty; i < 32; i += 8) {
    int c = c0 + i, p = p0 + tx;
    tile[i][tx] = (p < HW) ? xb[(size_t)c * HW + p] : 0.f;
  }
  __syncthreads();
  for (int i = ty; i < 32; i += 8) {
    int p = p0 + i, c = c0 + tx;
    if (p < HW) xtb[(size_t)p * C + c] = __float2bfloat16(tile[tx][i]);
  }
}

// x1 (N,256,50,50) -> srcb rows [10000,12500) bf16 only
__global__ __launch_bounds__(256) void copy_lvl1_in_k(const float* __restrict__ x,
    __hip_bfloat16* __restrict__ srcb)
{
  __shared__ float tile[32][33];
  int p0 = blockIdx.x * 32, c0 = blockIdx.y * 32, n = blockIdx.z;
  int tx = threadIdx.x & 31, ty = threadIdx.x >> 5;
  for (int i = ty; i < 32; i += 8) {
    int c = c0 + i, p = p0 + tx;
    tile[i][tx] = (p < 2500) ? x[((size_t)n * 256 + c) * 2500 + p] : 0.f;
  }
  __syncthreads();
  for (int i = ty; i < 32; i += 8) {
    int p = p0 + i, c = c0 + tx;
    if (p < 2500)
      srcb[((size_t)(n * LTOT + 10000 + p)) * 256 + c] = __float2bfloat16(tile[tx][i]);
  }
}

// h2b rows [10000,12500) bf16 -> out1 (N,256,50,50) f32
__global__ __launch_bounds__(256) void copy_lvl1_out_k(const __hip_bfloat16* __restrict__ h2,
                                                       float* __restrict__ out)
{
  __shared__ float tile[32][33];
  int p0 = blockIdx.x * 32, c0 = blockIdx.y * 32, n = blockIdx.z;
  int tx = threadIdx.x & 31, ty = threadIdx.x >> 5;
  for (int i = ty; i < 32; i += 8) {
    int p = p0 + i, c = c0 + tx;
    tile[tx][i] = (p < 2500) ? b2f(h2[((size_t)(n * LTOT + 10000 + p)) * 256 + c]) : 0.f;
  }
  __syncthreads();
  for (int i = ty; i < 32; i += 8) {
    int c = c0 + i, p = p0 + tx;
    if (p < 2500) out[((size_t)n * 256 + c) * 2500 + p] = tile[i][tx];
  }
}

// GroupNorm raw sums, coalesced full-row reads; atomics into stats[64g][2]
__global__ __launch_bounds__(256) void gn_stats_k(const float* __restrict__ src,
                                                  float* __restrict__ stats)
{
  int b = blockIdx.x, n = blockIdx.y, t = threadIdx.x;
  int li, off, rr0, rend;
  if (b < 157)      { li = 0; off = 0;     rr0 = b * 64;         rend = min(rr0 + 64, 10000); }
  else if (b < 167) { li = 1; off = 12500; rr0 = (b - 157) * 64; rend = min(rr0 + 64, 625); }
  else if (b < 170) { li = 2; off = 13125; rr0 = (b - 167) * 64; rend = min(rr0 + 64, 169); }
  else              { li = 3; off = 13294; rr0 = 0;              rend = 49; }
  const float* base = src + ((size_t)(n * LTOT + off)) * 256 + t;
  float s = 0.f, s2 = 0.f;
  for (int r = rr0; r < rend; r++) {
    float v = base[(size_t)r * 256];
    s += v; s2 += v * v;
  }
  s  += __shfl_down(s, 4, 64);  s2 += __shfl_down(s2, 4, 64);
  s  += __shfl_down(s, 2, 64);  s2 += __shfl_down(s2, 2, 64);
  s  += __shfl_down(s, 1, 64);  s2 += __shfl_down(s2, 1, 64);
  if ((t & 7) == 0) {
    int g = t >> 3;
    int si = (li * 2 + n) * 32 + g;
    atomicAdd(&stats[si * 2],     s);
    atomicAdd(&stats[si * 2 + 1], s2);
  }
}

// merged GN apply + finalize -> bf16 only; grid 21686 blocks
__global__ __launch_bounds__(256) void gn_apply_k(const float* __restrict__ src,
    __hip_bfloat16* __restrict__ srcb,
    const float* __restrict__ stats, const float* __restrict__ g,
    const float* __restrict__ b)
{
  int x = blockIdx.x;
  int n = x / 10843, cidx = x - n * 10843;
  int li, off, hw, p;
  if (cidx < 10000)      { li = 0; off = 0;     hw = 10000; p = cidx; }
  else if (cidx < 10625) { li = 1; off = 12500; hw = 625;   p = cidx - 10000; }
  else if (cidx < 10794) { li = 2; off = 13125; hw = 169;   p = cidx - 10625; }
  else                   { li = 3; off = 13294; hw = 49;    p = cidx - 10794; }
  int t = threadIdx.x;
  int si = (li * 2 + n) * 32 + (t >> 3);
  float cnt = (float)(hw * 8);
  float mean = stats[si * 2] / cnt;
  float var = stats[si * 2 + 1] / cnt - mean * mean;
  float rstd = rsqrtf(var + 1e-5f);
  size_t a = ((size_t)(n * LTOT + off + p)) * 256 + t;
  float v = (src[a] - mean) * rstd * g[t] + b[t];
  srcb[a] = __float2bfloat16(v);
}

// ---------------------------------------------------------------------------
// deformable sampling v6b (PROVEN OPTIMUM — rounds 6/7/13 wider variants all
// lost to occupancy/conflict displacement): block = 2 queries; fused softmax;
// f16 value/off/aw; gather 2 ch/thread via dword load + packed f16 fma.
// LDS ~12 KB, VGPR 32, conflicts 0.
// ---------------------------------------------------------------------------
__global__ __launch_bounds__(256) void msdeform_k(const _Float16* __restrict__ value,
    const _Float16* __restrict__ offb, const _Float16* __restrict__ awb,
    const float* __restrict__ refb, __hip_bfloat16* __restrict__ out)
{
  __shared__ float s_awraw[320];
  __shared__ float s_ref[20];
  __shared__ float s_stat[32];
  __shared__ int4 s_cA[320];   // [ql*160 + h*20+pt] -> off00,w00p,off10,w10p
  __shared__ int4 s_cB[320];   //                     -> off01,w01p,off11,w11p
  const int t = threadIdx.x;
  const int q0 = blockIdx.x * 2;

  for (int i = t; i < 320; i += 256) {
    int ql = (i >= 160) ? 1 : 0;
    s_awraw[i] = (float)awb[(size_t)(q0 + ql) * 160 + (i - ql * 160)];
  }
  if (t < 20) {
    int ql = (t >= 10) ? 1 : 0;
    s_ref[t] = refb[(size_t)(q0 + ql) * 10 + (t - ql * 10)];
  }
  __syncthreads();

  if (t < 16) {
    const float* p = s_awraw + t * 20;
    float m = p[0];
#pragma unroll
    for (int j = 1; j < 20; j++) m = fmaxf(m, p[j]);
    float s = 0.f;
#pragma unroll
    for (int j = 0; j < 20; j++) s += expf(p[j] - m);
    s_stat[t * 2] = m;
    s_stat[t * 2 + 1] = 1.f / s;
  }
  __syncthreads();

  {
    const int Wl[5]   = {100, 50, 25, 13, 7};
    const int lvlo[5] = {0, 10000, 12500, 13125, 13294};
    for (int i = t; i < 320; i += 256) {
      int ql = (i >= 160) ? 1 : 0;
      int j = i - ql * 160;
      int h = j / 20, pt = j - h * 20;
      int l = pt >> 2;
      int q = q0 + ql;
      int W = Wl[l], lo = lvlo[l];
      float fW = (float)W;
      f16x2 o2h = *(const f16x2*)(offb + (size_t)q * 320 + j * 2);
      float ox = (float)o2h[0], oy = (float)o2h[1];
      int hs = (ql * 8 + h) * 2;
      float wgt = expf(s_awraw[i] - s_stat[hs]) * s_stat[hs + 1];
      float rx = s_ref[ql * 10 + l * 2], ry = s_ref[ql * 10 + l * 2 + 1];
      float x = (rx + ox / fW) * fW - 0.5f;
      float y = (ry + oy / fW) * fW - 0.5f;
      float x0f = floorf(x), y0f = floorf(y);
      float wx = x - x0f, wy = y - y0f;
      int x0 = (int)x0f, y0 = (int)y0f;
      int hb = h * 64;
      auto mk = [&](int ix, int iy, float w) {
        bool v = (ix >= 0) & (ix < W) & (iy >= 0) & (iy < W);
        int cx = min(max(ix, 0), W - 1), cy = min(max(iy, 0), W - 1);
        int off = (lo + cy * W + cx) * 512 + hb;
        float fw = v ? w * wgt : 0.f;
        unsigned hbits = (unsigned)__builtin_bit_cast(unsigned short, (_Float16)fw);
        return make_int2(off, (int)(hbits | (hbits << 16)));
      };
      int2 c00 = mk(x0,     y0,     (1.f - wx) * (1.f - wy));
      int2 c10 = mk(x0 + 1, y0,     wx * (1.f - wy));
      int2 c01 = mk(x0,     y0 + 1, (1.f - wx) * wy);
      int2 c11 = mk(x0 + 1, y0 + 1, wx * wy);
      s_cA[i] = make_int4(c00.x, c00.y, c10.x, c10.y);
      s_cB[i] = make_int4(c01.x, c01.y, c11.x, c11.y);
    }
  }
  __syncthreads();

  const int ql = t >> 7, h = (t >> 4) & 7, c2 = t & 15;
  const int q = q0 + ql;
  const int n = q / LTOT;
  const char* vb = (const char*)value + (size_t)n * LTOT * 512 + c2 * 4;
  f16x2 accA = {0, 0}, accB = {0, 0};
  const int bi = ql * 160 + h * 20;
#pragma unroll 5
  for (int p = 0; p < 20; p++) {
    int4 A = s_cA[bi + p];
    int4 B = s_cB[bi + p];
    {
      f16x2 v2 = __builtin_bit_cast(f16x2, *(const unsigned*)(vb + A.x));
      f16x2 w2 = __builtin_bit_cast(f16x2, (unsigned)A.y);
      accA = w2 * v2 + accA;
    }
    {
      f16x2 v2 = __builtin_bit_cast(f16x2, *(const unsigned*)(vb + A.z));
      f16x2 w2 = __builtin_bit_cast(f16x2, (unsigned)A.w);
      accB = w2 * v2 + accB;
    }
    {
      f16x2 v2 = __builtin_bit_cast(f16x2, *(const unsigned*)(vb + B.x));
      f16x2 w2 = __builtin_bit_cast(f16x2, (unsigned)B.y);
      accA = w2 * v2 + accA;
    }
    {
      f16x2 v2 = __builtin_bit_cast(f16x2, *(const unsigned*)(vb + B.z));
      f16x2 w2 = __builtin_bit_cast(f16x2, (unsigned)B.w);
      accB = w2 * v2 + accB;
    }
  }
  float a0 = (float)accA[0] + (float)accB[0];
  float a1 = (float)accA[1] + (float)accB[1];
  unsigned o0 = (unsigned)f2bu(a0);
  unsigned o1 = (unsigned)f2bu(a1);
  *(unsigned*)((char*)out + ((size_t)q * 256 + h * 32 + c2 * 2) * 2) = (o1 << 16) | o0;
}

// o = LayerNorm(x) over 256, bf16 I/O; wave-per-row (4 rows/block), no LDS
__global__ __launch_bounds__(256) void ln_k(const __hip_bfloat16* __restrict__ x,
    __hip_bfloat16* __restrict__ o, const float* __restrict__ g,
    const float* __restrict__ b)
{
  int wv = threadIdx.x >> 6, lane = threadIdx.x & 63;
  int row = blockIdx.x * 4 + wv;
  if (row >= NLQ) return;
  int e = lane * 4;
  ushort4 u = *(const ushort4*)((const char*)x + ((size_t)row * 256 + e) * 2);
  float v0 = __int_as_float((int)u.x << 16);
  float v1 = __int_as_float((int)u.y << 16);
  float v2 = __int_as_float((int)u.z << 16);
  float v3 = __int_as_float((int)u.w << 16);
  float s = v0 + v1 + v2 + v3;
#pragma unroll
  for (int off = 32; off; off >>= 1) s += __shfl_xor(s, off, 64);
  float mean = s * (1.f / 256.f);
  float d0 = v0 - mean, d1 = v1 - mean, d2 = v2 - mean, d3 = v3 - mean;
  float s2 = d0 * d0 + d1 * d1 + d2 * d2 + d3 * d3;
#pragma unroll
  for (int off = 32; off; off >>= 1) s2 += __shfl_xor(s2, off, 64);
  float rstd = rsqrtf(s2 * (1.f / 256.f) + 1e-5f);
  float4 gv = *(const float4*)(g + e);
  float4 bvv = *(const float4*)(b + e);
  ushort4 w;
  w.x = f2bu(d0 * rstd * gv.x + bvv.x);
  w.y = f2bu(d1 * rstd * gv.y + bvv.y);
  w.z = f2bu(d2 * rstd * gv.z + bvv.z);
  w.w = f2bu(d3 * rstd * gv.w + bvv.w);
  *(ushort4*)((char*)o + ((size_t)row * 256 + e) * 2) = w;
}

extern "C" void kernel_launch(void* const* d_in, const int* in_sizes, int n_in,
                              void* d_out, int out_size, void* d_ws, size_t ws_size,
                              hipStream_t stream)
{
  const float* x0    = (const float*)d_in[0];
  const float* x1    = (const float*)d_in[1];
  const float* x2    = (const float*)d_in[2];
  const float* x3    = (const float*)d_in[3];
  const float* W_ref = (const float*)d_in[4];
  const float* b_ref = (const float*)d_in[5];
  const float* W_off = (const float*)d_in[6];
  const float* b_off = (const float*)d_in[7];
  const float* W_aw  = (const float*)d_in[8];
  const float* b_aw  = (const float*)d_in[9];
  const float* W_val = (const float*)d_in[10];
  const float* b_val = (const float*)d_in[11];
  const float* W_outp= (const float*)d_in[12];
  const float* b_outp= (const float*)d_in[13];
  const float* gn_g  = (const float*)d_in[14];
  const float* gn_b  = (const float*)d_in[15];
  const float* Wc1   = (const float*)d_in[16];
  const float* bc1   = (const float*)d_in[17];
  const float* Wc2   = (const float*)d_in[18];
  const float* bc2   = (const float*)d_in[19];
  const float* Wc3   = (const float*)d_in[20];
  const float* bc3   = (const float*)d_in[21];
  const float* Wc4   = (const float*)d_in[22];
  const float* bc4   = (const float*)d_in[23];
  const float* Wc11  = (const float*)d_in[24];
  const float* bc11  = (const float*)d_in[25];
  const float* Wc22  = (const float*)d_in[26];
  const float* bc22  = (const float*)d_in[27];
  const float* Wc33  = (const float*)d_in[28];
  const float* bc33  = (const float*)d_in[29];
  const float* ln1_g = (const float*)d_in[30];
  const float* ln1_b = (const float*)d_in[31];
  const float* W1    = (const float*)d_in[32];
  const float* b1f   = (const float*)d_in[33];
  const float* W2    = (const float*)d_in[34];
  const float* b2f_  = (const float*)d_in[35];
  const float* ln2_g = (const float*)d_in[36];
  const float* ln2_b = (const float*)d_in[37];

  // ---- workspace (byte offsets) ----
  char* wsb = (char*)d_ws;
  float* src             = (float*)(wsb + 0);
  _Float16* valb         = (_Float16*)(wsb + WS_VALB);
  __hip_bfloat16* h1pre  = (__hip_bfloat16*)(wsb + 54652928);
  __hip_bfloat16* h2b    = h1pre;
  __hip_bfloat16* srcb   = (__hip_bfloat16*)(wsb + 81979392);
  __hip_bfloat16* h1b    = (__hip_bfloat16*)(wsb + 95642624);
  __hip_bfloat16* sampb  = (__hip_bfloat16*)(wsb + 109305856);
  __hip_bfloat16* h2pre  = sampb;
  __hip_bfloat16* midb   = (__hip_bfloat16*)(wsb + WS_R);
  _Float16* offbh        = (_Float16*)(wsb + WS_R);
  _Float16* awbh         = (_Float16*)(wsb + WS_AW);
  float* refb            = (float*)(wsb + WS_REF);
  __hip_bfloat16* xt0    = (__hip_bfloat16*)(wsb + WS_R);
  __hip_bfloat16* xt2    = (__hip_bfloat16*)(wsb + WS_R + 5120000);
  __hip_bfloat16* xt3    = (__hip_bfloat16*)(wsb + WS_R + 6400000);
  __hip_bfloat16* warena = (__hip_bfloat16*)(wsb + 177622016);
  float* stats           = (float*)(wsb + 180887552);
  float* catbias         = (float*)(wsb + 180889600);
  const size_t needed = 180892672;
  if (ws_size < needed) return;

  __hip_bfloat16* wWproj = warena + 0;
  __hip_bfloat16* wW_val = warena + 0;
  __hip_bfloat16* wW_off = warena + 65536;
  __hip_bfloat16* wW_aw  = warena + 147456;
  __hip_bfloat16* wW_ref = warena + 188416;
  __hip_bfloat16* wW_out = warena + 190976;
  __hip_bfloat16* wW1    = warena + 256512;
  __hip_bfloat16* wW2    = warena + 518656;
  __hip_bfloat16* wWc1   = warena + 780800;
  __hip_bfloat16* wWc2   = warena + 813568;
  __hip_bfloat16* wWc3   = warena + 944640;
  __hip_bfloat16* wWc11  = warena + 1206784;
  __hip_bfloat16* wWc22  = warena + 1239552;
  __hip_bfloat16* wWc33  = warena + 1370624;

  dim3 B(256);

  CvtTab tab = {{
    {W_val, wW_val, 65536}, {W_off, wW_off, 81920}, {W_aw, wW_aw, 40960},
    {W_ref, wW_ref, 2560},  {W_outp, wW_out, 65536},{W1, wW1, 262144},
    {W2, wW2, 262144},      {Wc1, wWc1, 32768},     {Wc2, wWc2, 131072},
    {Wc3, wWc3, 262144},    {Wc11, wWc11, 32768},   {Wc22, wWc22, 131072},
    {Wc33, wWc33, 262144}
  }};
  cvt_weights_k<<<dim3(1024,15),B,0,stream>>>(tab, b_val, b_off, b_aw, b_ref,
                                              catbias, stats, src, bc4);

  // ---- phase 1: fused transposes, convs, GN into src/srcb ----
  transpose_all_k<<<3528,B,0,stream>>>(x0, x2, x3, xt0, xt2, xt3);
  mgemm_k<64,0,0,0><<<dim3(313,2),B,0,stream>>>(xt0, wWc1, bc1, src, nullptr, 20000,256,128,128, 20000,0,0, 10000,LTOT,0);
  mgemm_k<64,0,0,0><<<dim3(20,2), B,0,stream>>>(xt2, wWc2, bc2, src, nullptr, 1250,256,512,512, 1250,0,0, 625,LTOT,12500);
  mgemm_k<64,0,0,0><<<dim3(6,2),  B,0,stream>>>(xt3, wWc3, bc3, src, nullptr, 338,256,1024,1024, 338,0,0, 169,LTOT,13125);
  mgemm_k<128,1,3,1><<<dim3(1,2,32),B,0,stream>>>(xt3, Wc4, bc4, src, nullptr, 98,256,9216,288, 0,0,0, 49,LTOT,13294);
  copy_lvl1_in_k<<<dim3(79,8,2),B,0,stream>>>(x1, srcb);
  gn_stats_k<<<dim3(171,2),B,0,stream>>>(src, stats);
  gn_apply_k<<<21686,B,0,stream>>>(src, srcb, stats, gn_g, gn_b);

  // ---- fused projections + sampling ----
  mgemm_k<128,0,7,0><<<dim3(209,6),B,0,stream>>>(srcb, wWproj, catbias, d_ws, nullptr, NLQ,746,256,256, NLQ,0,0, NLQ,0,0);
  msdeform_k<<<13343,B,0,stream>>>(valb, offbh, awbh, refb, sampb);

  // ---- out-proj (+resid srcb) + LN1 ----
  mgemm_k<64,0,8,0><<<dim3(417,2),B,0,stream>>>(sampb, wW_out, b_outp, h1pre, srcb, NLQ,256,256,256, NLQ,0,0, NLQ,0,0);
  ln_k<<<6672,B,0,stream>>>(h1pre, h1b, ln1_g, ln1_b);

  // ---- FFN (+resid h1b on FFN2) + LN2 ----
  mgemm_k<128,0,2,0><<<dim3(209,8),B,0,stream>>>(h1b,  wW1, b1f,  midb,  nullptr, NLQ,1024,256,256, NLQ,0,0, NLQ,0,0);
  mgemm_k<64,0,8,0><<<dim3(417,2), B,0,stream>>>(midb, wW2, b2f_, h2pre, h1b, NLQ,256,1024,1024, NLQ,0,0, NLQ,0,0);
  ln_k<<<6672,B,0,stream>>>(h2pre, h2b, ln2_g, ln2_b);

  // ---- output convs / copies (MT64) ----
  float* out = (float*)d_out;
  mgemm_k<64,0,4,0><<<dim3(313,1),B,0,stream>>>(h2b, wWc11, bc11, out,           nullptr, 20000,128,256,256, 10000,LTOT,0,   10000,0,0);
  copy_lvl1_out_k<<<dim3(79,8,2),B,0,stream>>>(h2b, out + 2560000);
  mgemm_k<64,0,4,0><<<dim3(20,4), B,0,stream>>>(h2b, wWc22, bc22, out + 3840000, nullptr, 1250,512,256,256,  625,LTOT,12500, 625,0,0);
  mgemm_k<64,0,4,0><<<dim3(6,8),  B,0,stream>>>(h2b, wWc33, bc33, out + 4480000, nullptr, 338,1024,256,256,  169,LTOT,13125, 169,0,0);
}